// Round 1
// baseline (48.069 us; speedup 1.0000x reference)
//
#include <hip/hip_runtime.h>

// InverseDaubechiesWaveletLayer: polyphase inverse DWT (db4), fused.
// in : [B=16, L=16000, 128] f32 (first 64 ch = approx, last 64 = detail)
// out: [B=16, 2L=32000, 64] f32
//
// Derivation: out = same_corr(upsample2(approx), rec_lo)
//                 + same_corr(upsample2(detail), rec_hi), pad L=3, R=4.
// up[2l]=z[l], up[2l+1]=0 =>
//   out[2m]   = sum_k z_a[m-1+k]*lo[2k+1] + z_d[m-1+k]*hi[2k+1]
//   out[2m+1] = sum_k z_a[m-1+k]*lo[2k]   + z_d[m-1+k]*hi[2k]   (k=0..3)

#define NB 16
#define NL 16000
#define MBLK 1000   // NL / 16 m-values per block

__global__ __launch_bounds__(256) void idwt_db4_kernel(
    const float* __restrict__ in,
    const float* __restrict__ rec_lo,
    const float* __restrict__ rec_hi,
    float* __restrict__ out)
{
    const int tid = threadIdx.x;
    const int c  = (tid & 15) * 4;   // channel offset 0..60 (float4 group)
    const int ml = tid >> 4;         // 0..15: m within block
    const int blk = blockIdx.x;
    const int b = blk / MBLK;
    const int m = (blk - b * MBLK) * 16 + ml;

    // Filters: uniform address -> scalar loads, L1-broadcast. Cheap.
    float lo[8], hi[8];
#pragma unroll
    for (int i = 0; i < 8; ++i) { lo[i] = rec_lo[i]; hi[i] = rec_hi[i]; }

    const long inBase = (long)b * NL * 128 + c;

    float4 a[4], d[4];
#pragma unroll
    for (int k = 0; k < 4; ++k) {
        const int l = m - 1 + k;
        if (l >= 0 && l < NL) {
            const float4* p = (const float4*)(in + inBase + (long)l * 128);
            a[k] = p[0];    // approx: ch c..c+3
            d[k] = p[16];   // detail: ch 64+c..64+c+3
        } else {
            a[k] = make_float4(0.f, 0.f, 0.f, 0.f);
            d[k] = make_float4(0.f, 0.f, 0.f, 0.f);
        }
    }

    float4 ev = make_float4(0.f, 0.f, 0.f, 0.f);
    float4 od = make_float4(0.f, 0.f, 0.f, 0.f);
#pragma unroll
    for (int k = 0; k < 4; ++k) {
        const float leA = lo[2*k + 1], leD = hi[2*k + 1];   // even-t taps
        const float loA = lo[2*k],     loD = hi[2*k];       // odd-t taps
        ev.x = fmaf(a[k].x, leA, fmaf(d[k].x, leD, ev.x));
        ev.y = fmaf(a[k].y, leA, fmaf(d[k].y, leD, ev.y));
        ev.z = fmaf(a[k].z, leA, fmaf(d[k].z, leD, ev.z));
        ev.w = fmaf(a[k].w, leA, fmaf(d[k].w, leD, ev.w));
        od.x = fmaf(a[k].x, loA, fmaf(d[k].x, loD, od.x));
        od.y = fmaf(a[k].y, loA, fmaf(d[k].y, loD, od.y));
        od.z = fmaf(a[k].z, loA, fmaf(d[k].z, loD, od.z));
        od.w = fmaf(a[k].w, loA, fmaf(d[k].w, loD, od.w));
    }

    const long outBase = ((long)b * (2 * NL) + 2 * m) * 64 + c;
    *(float4*)(out + outBase)      = ev;   // t = 2m
    *(float4*)(out + outBase + 64) = od;   // t = 2m+1
}

extern "C" void kernel_launch(void* const* d_in, const int* in_sizes, int n_in,
                              void* d_out, int out_size, void* d_ws, size_t ws_size,
                              hipStream_t stream)
{
    const float* in     = (const float*)d_in[0];
    const float* rec_lo = (const float*)d_in[1];
    const float* rec_hi = (const float*)d_in[2];
    float* out = (float*)d_out;

    // Grid: 16 batches * 1000 m-blocks; block = 16 m * 16 channel-quads
    dim3 grid(NB * MBLK);
    dim3 block(256);
    idwt_db4_kernel<<<grid, block, 0, stream>>>(in, rec_lo, rec_hi, out);
}